// Round 8
// baseline (280.140 us; speedup 1.0000x reference)
//
#include <hip/hip_runtime.h>
#include <hip/hip_bf16.h>
#include <cstdint>

#define N_NODES 100000
#define N_EDGES 1600000
#define DIM 128
#define K2 256
#define ODIM 64
#define NPB 64
#define CB 98            // coarse buckets: dst>>10 (1024 nodes each)
#define NREP 8           // replicas (one per XCD via blockIdx&7 heuristic)
#define CAP1 2560        // per (rep,bucket) capacity: mean ~2048, +11 sigma
#define EPB 4096         // edges per k_bucket block

typedef __hip_bfloat16 bf16;
typedef __attribute__((ext_vector_type(8))) short bfrag;   // 8 bf16 = 4 VGPRs
typedef __attribute__((ext_vector_type(4))) float f32x4;

// ---------------- bucket binning: LDS-sort 4096 edges by coarse key, bulk-append ----------------
__global__ __launch_bounds__(1024) void k_bucket(const int* __restrict__ src,
                                                 const int* __restrict__ dst,
                                                 int* __restrict__ gcur,
                                                 uint32_t* __restrict__ bdata) {
  __shared__ int hist[CB], hbase[CB], hcur[CB], gstart[CB];
  __shared__ uint32_t ent[EPB];
  __shared__ uint8_t kslot[EPB];
  const int tid = threadIdx.x;
  const int rep = blockIdx.x & (NREP - 1);
  const int e0 = blockIdx.x * EPB;
  const int cnt = min(EPB, N_EDGES - e0);

  if (tid < CB) { hist[tid] = 0; hcur[tid] = 0; }
  __syncthreads();

  const int me0 = e0 + tid * 4;
  int ss[4], dd[4];
  int nmine = max(0, min(4, N_EDGES - me0));
  if (nmine == 4) {
    *(int4*)ss = *(const int4*)(src + me0);
    *(int4*)dd = *(const int4*)(dst + me0);
  } else {
    for (int q = 0; q < nmine; ++q) { ss[q] = src[me0 + q]; dd[q] = dst[me0 + q]; }
  }

#pragma unroll
  for (int q = 0; q < 4; ++q)
    if (q < nmine) atomicAdd(&hist[dd[q] >> 10], 1);
  __syncthreads();

  if (tid == 0) {
    int run = 0;
    for (int b = 0; b < CB; ++b) { hbase[b] = run; run += hist[b]; }
  }
  __syncthreads();

#pragma unroll
  for (int q = 0; q < 4; ++q)
    if (q < nmine) {
      int key = dd[q] >> 10;
      int r = atomicAdd(&hcur[key], 1);
      int p = hbase[key] + r;
      ent[p] = ((uint32_t)ss[q] << 10) | (uint32_t)(dd[q] & 1023);
      kslot[p] = (uint8_t)key;
    }
  __syncthreads();

  if (tid < CB && hist[tid] > 0)
    gstart[tid] = atomicAdd(&gcur[rep * CB + tid], hist[tid]);
  __syncthreads();

  for (int i = tid; i < cnt; i += 1024) {
    int k = kslot[i];
    int pos = gstart[k] + (i - hbase[k]);
    if (pos < CAP1)
      bdata[((size_t)(rep * CB + k)) * CAP1 + pos] = ent[i];
  }
}

// ---------------- per-coarse-bucket CSR: 1024-node hist + scan + rank scatter ----------------
__global__ __launch_bounds__(256) void k_csr(const uint32_t* __restrict__ bdata,
                                             const int* __restrict__ gcur,
                                             int* __restrict__ rowptr,
                                             int* __restrict__ col) {
  __shared__ int nc[1024], noff[1024];
  __shared__ int red[256];
  __shared__ int sz[NREP];
  const int b = blockIdx.x, tid = threadIdx.x;

  if (tid < NREP) sz[tid] = min(gcur[tid * CB + b], CAP1);

  int part = 0;
  for (int i = tid; i < NREP * b; i += 256) {
    int bp = i >> 3, r = i & 7;
    part += min(gcur[r * CB + bp], CAP1);
  }
  red[tid] = part;
  __syncthreads();
  for (int off = 128; off > 0; off >>= 1) {
    if (tid < off) red[tid] += red[tid + off];
    __syncthreads();
  }
  const int base = red[0];
  __syncthreads();

  for (int i = tid; i < 1024; i += 256) nc[i] = 0;
  __syncthreads();

  for (int r = 0; r < NREP; ++r) {
    int c = sz[r];
    const uint32_t* seg = bdata + ((size_t)(r * CB + b)) * CAP1;
    for (int i = tid; i < c; i += 256)
      atomicAdd(&nc[seg[i] & 1023], 1);
  }
  __syncthreads();

  int loc[4], s = 0;
#pragma unroll
  for (int q = 0; q < 4; ++q) { loc[q] = nc[tid * 4 + q]; s += loc[q]; }
  red[tid] = s;
  __syncthreads();
  for (int off = 1; off < 256; off <<= 1) {
    int add = (tid >= off) ? red[tid - off] : 0;
    __syncthreads();
    red[tid] += add;
    __syncthreads();
  }
  int p = red[tid] - s;
#pragma unroll
  for (int q = 0; q < 4; ++q) { noff[tid * 4 + q] = p; p += loc[q]; }
  __syncthreads();

  for (int i = tid; i < 1024; i += 256) {
    int n = b * 1024 + i;
    if (n < N_NODES) rowptr[n] = base + noff[i];
  }
  if (b == 0 && tid == 0) rowptr[N_NODES] = N_EDGES;

  for (int i = tid; i < 1024; i += 256) nc[i] = 0;
  __syncthreads();

  for (int r = 0; r < NREP; ++r) {
    int c = sz[r];
    const uint32_t* seg = bdata + ((size_t)(r * CB + b)) * CAP1;
    for (int i = tid; i < c; i += 256) {
      uint32_t e = seg[i];
      int n = e & 1023;
      int pos = atomicAdd(&nc[n], 1);
      col[base + noff[n] + pos] = (int)(e >> 10);
    }
  }
}

// ---------------- precompute: x -> bf16 ----------------
__global__ __launch_bounds__(256) void k_cvt(const float* __restrict__ x,
                                             bf16* __restrict__ xb) {
  int i = (blockIdx.x * 256 + threadIdx.x) * 4;
  if (i >= N_NODES * DIM) return;
  float4 v = *(const float4*)(x + i);
  bf16 t[4];
  t[0] = __float2bfloat16(v.x);
  t[1] = __float2bfloat16(v.y);
  t[2] = __float2bfloat16(v.z);
  t[3] = __float2bfloat16(v.w);
  *(uint2*)(xb + i) = *(uint2*)t;
}

// ---------------- precompute: pack weights transposed bf16 ----------------
__global__ __launch_bounds__(256) void k_prepw(const float* __restrict__ wl0,
                                               const float* __restrict__ wr0,
                                               const float* __restrict__ wl1,
                                               const float* __restrict__ wr1,
                                               const float* __restrict__ wo,
                                               bf16* __restrict__ WT0,
                                               bf16* __restrict__ WT1,
                                               bf16* __restrict__ WoT) {
  int g = blockIdx.x * 256 + threadIdx.x;
  if (g < 32768) {
    int j = g >> 8, k = g & 255;
    float v = (k < DIM) ? wl0[k * DIM + j] : wr0[(k - DIM) * DIM + j];
    WT0[g] = __float2bfloat16(v);
  } else if (g < 65536) {
    int gg = g - 32768;
    int j = gg >> 8, k = gg & 255;
    float v = (k < DIM) ? wl1[k * DIM + j] : wr1[(k - DIM) * DIM + j];
    WT1[gg] = __float2bfloat16(v);
  } else if (g < 65536 + 8192) {
    int gg = g - 65536;
    int j = gg >> 7, k = gg & 127;
    WoT[gg] = __float2bfloat16(wo[k * ODIM + j]);
  }
}

// ---------------- gather helpers ----------------
__device__ __forceinline__ void acc8(float* acc, uint4 v) {
  acc[0] += __uint_as_float(v.x << 16);
  acc[1] += __uint_as_float(v.x & 0xFFFF0000u);
  acc[2] += __uint_as_float(v.y << 16);
  acc[3] += __uint_as_float(v.y & 0xFFFF0000u);
  acc[4] += __uint_as_float(v.z << 16);
  acc[5] += __uint_as_float(v.z & 0xFFFF0000u);
  acc[6] += __uint_as_float(v.w << 16);
  acc[7] += __uint_as_float(v.w & 0xFFFF0000u);
}

// Wave-cooperative gather+mean of one node row into lanes g==0 (16 lanes x 8 feats),
// then pack bf16 and ds_write into the swizzled A-tile.
__device__ __forceinline__ void gather_row(const bf16* __restrict__ feat,
                                           const int* __restrict__ col,
                                           int beg, int end, int g, int lg,
                                           int row, char* sA) {
  float acc[8];
#pragma unroll
  for (int q = 0; q < 8; ++q) acc[q] = 0.f;

  int j = beg;
  for (; j + 16 <= end; j += 16) {
    int s0 = col[j + g];
    int s1 = col[j + 4 + g];
    int s2 = col[j + 8 + g];
    int s3 = col[j + 12 + g];
    uint4 v0 = *(const uint4*)(feat + (size_t)s0 * DIM + lg * 8);
    uint4 v1 = *(const uint4*)(feat + (size_t)s1 * DIM + lg * 8);
    uint4 v2 = *(const uint4*)(feat + (size_t)s2 * DIM + lg * 8);
    uint4 v3 = *(const uint4*)(feat + (size_t)s3 * DIM + lg * 8);
    acc8(acc, v0); acc8(acc, v1); acc8(acc, v2); acc8(acc, v3);
  }
  for (; j + 4 <= end; j += 4) {
    int s = col[j + g];
    uint4 v = *(const uint4*)(feat + (size_t)s * DIM + lg * 8);
    acc8(acc, v);
  }
  int rem = end - j;
  if (g < rem) {
    int s = col[j + g];
    uint4 v = *(const uint4*)(feat + (size_t)s * DIM + lg * 8);
    acc8(acc, v);
  }

#pragma unroll
  for (int q = 0; q < 8; ++q) {
    acc[q] += __shfl_xor(acc[q], 16, 64);
    acc[q] += __shfl_xor(acc[q], 32, 64);
  }

  if (g == 0) {
    float inv = (end > beg) ? 1.0f / (float)(end - beg) : 0.f;
    union { uint32_t u[4]; uint4 v; } o;
#pragma unroll
    for (int q = 0; q < 4; ++q) {
      __hip_bfloat162 h;
      h.x = __float2bfloat16(acc[2 * q] * inv);
      h.y = __float2bfloat16(acc[2 * q + 1] * inv);
      o.u[q] = *(uint32_t*)&h;
    }
    int byte = (row * 512 + lg * 16) ^ ((row & 7) << 4);
    *(uint4*)(sA + byte) = o.v;
  }
}

// ---------------- fused layer 0: h = relu([mean-gather(xb) | xb] @ WT^T + b) ----------------
__global__ __launch_bounds__(256) void k_sage_f(const bf16* __restrict__ xs,
                                                const int* __restrict__ rowptr,
                                                const int* __restrict__ col,
                                                const bf16* __restrict__ WT,
                                                const float* __restrict__ bias,
                                                bf16* __restrict__ hout) {
  __shared__ char sA[NPB * 512];   // 32 KB: [64 rows][agg 256B | x 256B], swizzled
  const int tid = threadIdx.x;
  const int base = blockIdx.x * NPB;
  const int w = tid >> 6, lane = tid & 63;

  // issue x-half loads early (written to LDS after gather)
  uint4 xv[4];
  int xbyte[4];
#pragma unroll
  for (int q = 0; q < 4; ++q) {
    int t = tid + q * 256;            // 0..1023
    int row = t >> 4, c = t & 15;
    int n = base + row;
    xv[q] = make_uint4(0, 0, 0, 0);
    if (n < N_NODES) xv[q] = *(const uint4*)(xs + (size_t)n * DIM + c * 8);
    xbyte[q] = (row * 512 + (16 + c) * 16) ^ ((row & 7) << 4);
  }

  // gather phase: wave w aggregates rows w*16 .. w*16+15
  const int g = lane >> 4, lg = lane & 15;
  const int first = base + w * 16;
  int rp = rowptr[min(first + lane, N_NODES)];   // lanes 0..16 carry rowptr[first..first+16]
#pragma unroll 1
  for (int i = 0; i < 16; ++i) {
    int node = first + i;
    int beg = __shfl(rp, i, 64), end = __shfl(rp, i + 1, 64);
    if (node >= N_NODES) { beg = 0; end = 0; }
    gather_row(xs, col, beg, end, g, lg, w * 16 + i, sA);
  }

#pragma unroll
  for (int q = 0; q < 4; ++q) *(uint4*)(sA + xbyte[q]) = xv[q];
  __syncthreads();

  const int j0 = w * 32;
  const int lrow = lane & 15, lk = lane >> 4;

  f32x4 acc[4][2];
#pragma unroll
  for (int mi = 0; mi < 4; ++mi)
#pragma unroll
    for (int ni = 0; ni < 2; ++ni)
      acc[mi][ni] = (f32x4){0.f, 0.f, 0.f, 0.f};

  for (int kt = 0; kt < 8; ++kt) {
    bfrag b0 = *(const bfrag*)(WT + (size_t)(j0 + lrow) * K2 + kt * 32 + lk * 8);
    bfrag b1 = *(const bfrag*)(WT + (size_t)(j0 + 16 + lrow) * K2 + kt * 32 + lk * 8);
#pragma unroll
    for (int mi = 0; mi < 4; ++mi) {
      int row = mi * 16 + lrow;
      int byte = (row * 512 + kt * 64 + lk * 16) ^ ((row & 7) << 4);
      bfrag a = *(const bfrag*)(sA + byte);
      acc[mi][0] = __builtin_amdgcn_mfma_f32_16x16x32_bf16(a, b0, acc[mi][0], 0, 0, 0);
      acc[mi][1] = __builtin_amdgcn_mfma_f32_16x16x32_bf16(a, b1, acc[mi][1], 0, 0, 0);
    }
  }

#pragma unroll
  for (int ni = 0; ni < 2; ++ni) {
    int colj = j0 + ni * 16 + lrow;
    float bv = bias[colj];
#pragma unroll
    for (int mi = 0; mi < 4; ++mi) {
#pragma unroll
      for (int r = 0; r < 4; ++r) {
        int n = base + mi * 16 + lk * 4 + r;
        if (n < N_NODES)
          hout[(size_t)n * DIM + colj] = __float2bfloat16(fmaxf(acc[mi][ni][r] + bv, 0.f));
      }
    }
  }
}

// ---------------- fused layer 1 + head ----------------
__global__ __launch_bounds__(256) void k_out_f(const bf16* __restrict__ hs,
                                               const int* __restrict__ rowptr,
                                               const int* __restrict__ col,
                                               const bf16* __restrict__ WT,
                                               const float* __restrict__ bias,
                                               const bf16* __restrict__ WoT,
                                               const float* __restrict__ bo,
                                               float* __restrict__ out) {
  __shared__ char sA[NPB * 512];
  const int tid = threadIdx.x;
  const int base = blockIdx.x * NPB;
  const int w = tid >> 6, lane = tid & 63;

  uint4 xv[4];
  int xbyte[4];
#pragma unroll
  for (int q = 0; q < 4; ++q) {
    int t = tid + q * 256;
    int row = t >> 4, c = t & 15;
    int n = base + row;
    xv[q] = make_uint4(0, 0, 0, 0);
    if (n < N_NODES) xv[q] = *(const uint4*)(hs + (size_t)n * DIM + c * 8);
    xbyte[q] = (row * 512 + (16 + c) * 16) ^ ((row & 7) << 4);
  }

  const int g = lane >> 4, lg = lane & 15;
  const int first = base + w * 16;
  int rp = rowptr[min(first + lane, N_NODES)];
#pragma unroll 1
  for (int i = 0; i < 16; ++i) {
    int node = first + i;
    int beg = __shfl(rp, i, 64), end = __shfl(rp, i + 1, 64);
    if (node >= N_NODES) { beg = 0; end = 0; }
    gather_row(hs, col, beg, end, g, lg, w * 16 + i, sA);
  }

#pragma unroll
  for (int q = 0; q < 4; ++q) *(uint4*)(sA + xbyte[q]) = xv[q];
  __syncthreads();

  const int j0 = w * 32;
  const int lrow = lane & 15, lk = lane >> 4;

  f32x4 acc[4][2];
#pragma unroll
  for (int mi = 0; mi < 4; ++mi)
#pragma unroll
    for (int ni = 0; ni < 2; ++ni)
      acc[mi][ni] = (f32x4){0.f, 0.f, 0.f, 0.f};

  for (int kt = 0; kt < 8; ++kt) {
    bfrag b0 = *(const bfrag*)(WT + (size_t)(j0 + lrow) * K2 + kt * 32 + lk * 8);
    bfrag b1 = *(const bfrag*)(WT + (size_t)(j0 + 16 + lrow) * K2 + kt * 32 + lk * 8);
#pragma unroll
    for (int mi = 0; mi < 4; ++mi) {
      int row = mi * 16 + lrow;
      int byte = (row * 512 + kt * 64 + lk * 16) ^ ((row & 7) << 4);
      bfrag a = *(const bfrag*)(sA + byte);
      acc[mi][0] = __builtin_amdgcn_mfma_f32_16x16x32_bf16(a, b0, acc[mi][0], 0, 0, 0);
      acc[mi][1] = __builtin_amdgcn_mfma_f32_16x16x32_bf16(a, b1, acc[mi][1], 0, 0, 0);
    }
  }

  __syncthreads();   // reuse sA as h1 tile [64 rows][256B], swizzled
#pragma unroll
  for (int ni = 0; ni < 2; ++ni) {
    int colj = j0 + ni * 16 + lrow;
    float bv = bias[colj];
#pragma unroll
    for (int mi = 0; mi < 4; ++mi) {
#pragma unroll
      for (int r = 0; r < 4; ++r) {
        int row = mi * 16 + lk * 4 + r;
        float v = fmaxf(acc[mi][ni][r] + bv, 0.f);
        int byte = (row * 256 + colj * 2) ^ ((row & 7) << 4);
        *(bf16*)(sA + byte) = __float2bfloat16(v);
      }
    }
  }
  __syncthreads();

  const int jo = w * 16;
  f32x4 acc2[4];
#pragma unroll
  for (int mi = 0; mi < 4; ++mi) acc2[mi] = (f32x4){0.f, 0.f, 0.f, 0.f};

#pragma unroll
  for (int kt = 0; kt < 4; ++kt) {
    bfrag b = *(const bfrag*)(WoT + (size_t)(jo + lrow) * DIM + kt * 32 + lk * 8);
#pragma unroll
    for (int mi = 0; mi < 4; ++mi) {
      int row = mi * 16 + lrow;
      int byte = (row * 256 + kt * 64 + lk * 16) ^ ((row & 7) << 4);
      bfrag a = *(const bfrag*)(sA + byte);
      acc2[mi] = __builtin_amdgcn_mfma_f32_16x16x32_bf16(a, b, acc2[mi], 0, 0, 0);
    }
  }

  int colj = jo + lrow;
  float bv = bo[colj];
#pragma unroll
  for (int mi = 0; mi < 4; ++mi) {
#pragma unroll
    for (int r = 0; r < 4; ++r) {
      int n = base + mi * 16 + lk * 4 + r;
      if (n < N_NODES)
        out[(size_t)n * ODIM + colj] = 1.f / (1.f + __expf(-(acc2[mi][r] + bv)));
    }
  }
}

extern "C" void kernel_launch(void* const* d_in, const int* in_sizes, int n_in,
                              void* d_out, int out_size, void* d_ws, size_t ws_size,
                              hipStream_t stream) {
  const float* x     = (const float*)d_in[0];
  const int*   ei    = (const int*)d_in[1];
  const float* w_l0  = (const float*)d_in[2];
  const float* b_l0  = (const float*)d_in[3];
  const float* w_r0  = (const float*)d_in[4];
  const float* w_l1  = (const float*)d_in[5];
  const float* b_l1  = (const float*)d_in[6];
  const float* w_r1  = (const float*)d_in[7];
  const float* w_out = (const float*)d_in[8];
  const float* b_out = (const float*)d_in[9];
  float* out = (float*)d_out;

  const int* src = ei;
  const int* dst = ei + N_EDGES;

  char* ws = (char*)d_ws;
  int*      rowptr = (int*)(ws);                          // 400,004 B
  int*      gcur   = (int*)(ws + (512u << 10));           // 3,136 B
  int*      col    = (int*)(ws + (1u << 20));             // 6.4 MB
  uint32_t* bdata  = (uint32_t*)(ws + (8u << 20));        // 8.03 MB (8 x 98 x 2560)
  bf16*     WT0    = (bf16*)(ws + (17u << 20));           // 64 KB
  bf16*     WT1    = (bf16*)(ws + (17u << 20) + 65536);   // 64 KB
  bf16*     WoT    = (bf16*)(ws + (17u << 20) + 131072);  // 16 KB
  bf16*     h0b    = (bf16*)(ws + (44ull << 20));         // 25.6 MB
  bf16*     xb     = (bf16*)(ws + (70ull << 20));         // 25.6 MB

  // --- precompute (independent of CSR) ---
  k_cvt  <<<(N_NODES * DIM / 4 + 255) / 256, 256, 0, stream>>>(x, xb);
  k_prepw<<<(65536 + 8192 + 255) / 256, 256, 0, stream>>>(w_l0, w_r0, w_l1, w_r1, w_out,
                                                          WT0, WT1, WoT);

  // --- CSR build: block-binned bucket sort -> per-bucket CSR ---
  hipMemsetAsync(gcur, 0, NREP * CB * sizeof(int), stream);
  k_bucket<<<(N_EDGES + EPB - 1) / EPB, 1024, 0, stream>>>(src, dst, gcur, bdata);
  k_csr   <<<CB, 256, 0, stream>>>(bdata, gcur, rowptr, col);

  const int gblocks = (N_NODES + NPB - 1) / NPB;

  // --- layer 0 (fused gather + GEMM) ---
  k_sage_f<<<gblocks, 256, 0, stream>>>(xb, rowptr, col, WT0, b_l0, h0b);

  // --- layer 1 + head (fused gather + GEMM + head) ---
  k_out_f<<<gblocks, 256, 0, stream>>>(h0b, rowptr, col, WT1, b_l1, WoT, b_out, out);
}

// Round 9
// 250.398 us; speedup vs baseline: 1.1188x; 1.1188x over previous
//
#include <hip/hip_runtime.h>
#include <hip/hip_bf16.h>
#include <cstdint>

#define N_NODES 100000
#define N_EDGES 1600000
#define DIM 128
#define K2 256
#define ODIM 64
#define NPB 64
#define CB 98            // coarse buckets: dst>>10 (1024 nodes each)
#define NREP 8           // replicas (one per XCD via blockIdx&7 heuristic)
#define CAP1 2560        // per (rep,bucket) capacity: mean ~2048, +11 sigma
#define EPB 4096         // edges per k_bucket block

typedef __hip_bfloat16 bf16;
typedef __attribute__((ext_vector_type(8))) short bfrag;   // 8 bf16 = 4 VGPRs
typedef __attribute__((ext_vector_type(4))) float f32x4;
typedef __attribute__((ext_vector_type(2))) float f32x2;

// ---------------- bucket binning: LDS-sort 4096 edges by coarse key, bulk-append ----------------
__global__ __launch_bounds__(1024) void k_bucket(const int* __restrict__ src,
                                                 const int* __restrict__ dst,
                                                 int* __restrict__ gcur,
                                                 uint32_t* __restrict__ bdata) {
  __shared__ int hist[CB], hbase[CB], hcur[CB], gstart[CB];
  __shared__ uint32_t ent[EPB];
  __shared__ uint8_t kslot[EPB];
  const int tid = threadIdx.x;
  const int rep = blockIdx.x & (NREP - 1);
  const int e0 = blockIdx.x * EPB;
  const int cnt = min(EPB, N_EDGES - e0);

  if (tid < CB) { hist[tid] = 0; hcur[tid] = 0; }
  __syncthreads();

  const int me0 = e0 + tid * 4;
  int ss[4], dd[4];
  int nmine = max(0, min(4, N_EDGES - me0));
  if (nmine == 4) {
    *(int4*)ss = *(const int4*)(src + me0);
    *(int4*)dd = *(const int4*)(dst + me0);
  } else {
    for (int q = 0; q < nmine; ++q) { ss[q] = src[me0 + q]; dd[q] = dst[me0 + q]; }
  }

#pragma unroll
  for (int q = 0; q < 4; ++q)
    if (q < nmine) atomicAdd(&hist[dd[q] >> 10], 1);
  __syncthreads();

  if (tid == 0) {
    int run = 0;
    for (int b = 0; b < CB; ++b) { hbase[b] = run; run += hist[b]; }
  }
  __syncthreads();

#pragma unroll
  for (int q = 0; q < 4; ++q)
    if (q < nmine) {
      int key = dd[q] >> 10;
      int r = atomicAdd(&hcur[key], 1);
      int p = hbase[key] + r;
      ent[p] = ((uint32_t)ss[q] << 10) | (uint32_t)(dd[q] & 1023);
      kslot[p] = (uint8_t)key;
    }
  __syncthreads();

  if (tid < CB && hist[tid] > 0)
    gstart[tid] = atomicAdd(&gcur[rep * CB + tid], hist[tid]);
  __syncthreads();

  for (int i = tid; i < cnt; i += 1024) {
    int k = kslot[i];
    int pos = gstart[k] + (i - hbase[k]);
    if (pos < CAP1)
      bdata[((size_t)(rep * CB + k)) * CAP1 + pos] = ent[i];
  }
}

// ---------------- per-coarse-bucket CSR: 1024-node hist + scan + rank scatter ----------------
// col[] stores BYTE offsets (src * 256) for the gather kernel.
__global__ __launch_bounds__(256) void k_csr(const uint32_t* __restrict__ bdata,
                                             const int* __restrict__ gcur,
                                             int* __restrict__ rowptr,
                                             int* __restrict__ col) {
  __shared__ int nc[1024], noff[1024];
  __shared__ int red[256];
  __shared__ int sz[NREP];
  const int b = blockIdx.x, tid = threadIdx.x;

  if (tid < NREP) sz[tid] = min(gcur[tid * CB + b], CAP1);

  int part = 0;
  for (int i = tid; i < NREP * b; i += 256) {
    int bp = i >> 3, r = i & 7;
    part += min(gcur[r * CB + bp], CAP1);
  }
  red[tid] = part;
  __syncthreads();
  for (int off = 128; off > 0; off >>= 1) {
    if (tid < off) red[tid] += red[tid + off];
    __syncthreads();
  }
  const int base = red[0];
  __syncthreads();

  for (int i = tid; i < 1024; i += 256) nc[i] = 0;
  __syncthreads();

  for (int r = 0; r < NREP; ++r) {
    int c = sz[r];
    const uint32_t* seg = bdata + ((size_t)(r * CB + b)) * CAP1;
    for (int i = tid; i < c; i += 256)
      atomicAdd(&nc[seg[i] & 1023], 1);
  }
  __syncthreads();

  int loc[4], s = 0;
#pragma unroll
  for (int q = 0; q < 4; ++q) { loc[q] = nc[tid * 4 + q]; s += loc[q]; }
  red[tid] = s;
  __syncthreads();
  for (int off = 1; off < 256; off <<= 1) {
    int add = (tid >= off) ? red[tid - off] : 0;
    __syncthreads();
    red[tid] += add;
    __syncthreads();
  }
  int p = red[tid] - s;
#pragma unroll
  for (int q = 0; q < 4; ++q) { noff[tid * 4 + q] = p; p += loc[q]; }
  __syncthreads();

  for (int i = tid; i < 1024; i += 256) {
    int n = b * 1024 + i;
    if (n < N_NODES) rowptr[n] = base + noff[i];
  }
  if (b == 0 && tid == 0) rowptr[N_NODES] = N_EDGES;

  for (int i = tid; i < 1024; i += 256) nc[i] = 0;
  __syncthreads();

  for (int r = 0; r < NREP; ++r) {
    int c = sz[r];
    const uint32_t* seg = bdata + ((size_t)(r * CB + b)) * CAP1;
    for (int i = tid; i < c; i += 256) {
      uint32_t e = seg[i];
      int n = e & 1023;
      int pos = atomicAdd(&nc[n], 1);
      col[base + noff[n] + pos] = (int)((e >> 10) << 8);   // byte offset: src * 256
    }
  }
}

// ---------------- precompute: x -> bf16 ----------------
__global__ __launch_bounds__(256) void k_cvt(const float* __restrict__ x,
                                             bf16* __restrict__ xb) {
  int i = (blockIdx.x * 256 + threadIdx.x) * 4;
  if (i >= N_NODES * DIM) return;
  float4 v = *(const float4*)(x + i);
  bf16 t[4];
  t[0] = __float2bfloat16(v.x);
  t[1] = __float2bfloat16(v.y);
  t[2] = __float2bfloat16(v.z);
  t[3] = __float2bfloat16(v.w);
  *(uint2*)(xb + i) = *(uint2*)t;
}

// ---------------- precompute: pack weights transposed bf16 ----------------
__global__ __launch_bounds__(256) void k_prepw(const float* __restrict__ wl0,
                                               const float* __restrict__ wr0,
                                               const float* __restrict__ wl1,
                                               const float* __restrict__ wr1,
                                               const float* __restrict__ wo,
                                               bf16* __restrict__ WT0,
                                               bf16* __restrict__ WT1,
                                               bf16* __restrict__ WoT) {
  int g = blockIdx.x * 256 + threadIdx.x;
  if (g < 32768) {
    int j = g >> 8, k = g & 255;
    float v = (k < DIM) ? wl0[k * DIM + j] : wr0[(k - DIM) * DIM + j];
    WT0[g] = __float2bfloat16(v);
  } else if (g < 65536) {
    int gg = g - 32768;
    int j = gg >> 8, k = gg & 255;
    float v = (k < DIM) ? wl1[k * DIM + j] : wr1[(k - DIM) * DIM + j];
    WT1[gg] = __float2bfloat16(v);
  } else if (g < 65536 + 8192) {
    int gg = g - 65536;
    int j = gg >> 7, k = gg & 127;
    WoT[gg] = __float2bfloat16(wo[k * ODIM + j]);
  }
}

// ---------------- pull aggregation: 1 wave/node, 16 edges in flight, packed adds ----------------
__device__ __forceinline__ void accv(f32x2* acc, uint4 v) {
  uint32_t ws[4] = {v.x, v.y, v.z, v.w};
#pragma unroll
  for (int q = 0; q < 4; ++q) {
    f32x2 t;
    t[0] = __uint_as_float(ws[q] << 16);
    t[1] = __uint_as_float(ws[q] & 0xFFFF0000u);
    acc[q] += t;                      // v_pk_add_f32
  }
}

__global__ __launch_bounds__(256) void k_agg(const bf16* __restrict__ feat,
                                             const int* __restrict__ rowptr,
                                             const int* __restrict__ colb,
                                             bf16* __restrict__ agg) {
  int gid = blockIdx.x * 256 + threadIdx.x;
  int node = gid >> 6;
  if (node >= N_NODES) return;
  int lane = gid & 63;
  int g = lane >> 4, lg = lane & 15;
  int beg = rowptr[node], end = rowptr[node + 1];
  const char* fb = (const char*)feat + lg * 16;

  f32x2 acc[4];
#pragma unroll
  for (int q = 0; q < 4; ++q) acc[q] = (f32x2){0.f, 0.f};

  int j = beg;
  // 16 edges in flight (4 groups x 4-deep)
  for (; j + 16 <= end; j += 16) {
    int o0 = colb[j + g];
    int o1 = colb[j + 4 + g];
    int o2 = colb[j + 8 + g];
    int o3 = colb[j + 12 + g];
    uint4 v0 = *(const uint4*)(fb + o0);
    uint4 v1 = *(const uint4*)(fb + o1);
    uint4 v2 = *(const uint4*)(fb + o2);
    uint4 v3 = *(const uint4*)(fb + o3);
    accv(acc, v0); accv(acc, v1); accv(acc, v2); accv(acc, v3);
  }
  for (; j + 4 <= end; j += 4) {
    int o = colb[j + g];
    uint4 v = *(const uint4*)(fb + o);
    accv(acc, v);
  }
  int rem = end - j;
  if (g < rem) {
    int o = colb[j + g];
    uint4 v = *(const uint4*)(fb + o);
    accv(acc, v);
  }

  // reduce across the 4 edge groups
#pragma unroll
  for (int q = 0; q < 4; ++q) {
#pragma unroll
    for (int c = 0; c < 2; ++c) {
      acc[q][c] += __shfl_xor(acc[q][c], 16, 64);
      acc[q][c] += __shfl_xor(acc[q][c], 32, 64);
    }
  }

  if (g == 0) {
    float inv = (end > beg) ? 1.0f / (float)(end - beg) : 0.f;
    union { uint32_t u[4]; uint4 v; } o;
#pragma unroll
    for (int q = 0; q < 4; ++q) {
      __hip_bfloat162 h;
      h.x = __float2bfloat16(acc[q][0] * inv);
      h.y = __float2bfloat16(acc[q][1] * inv);
      o.u[q] = *(uint32_t*)&h;
    }
    *(uint4*)(agg + (size_t)node * DIM + lg * 8) = o.v;
  }
}

// ---------------- MFMA SAGE layer: h = relu([agg|x] @ WT^T + b) ----------------
__global__ __launch_bounds__(256) void k_sage(const bf16* __restrict__ agg,
                                              const bf16* __restrict__ xb,
                                              const bf16* __restrict__ WT,
                                              const float* __restrict__ bias,
                                              bf16* __restrict__ hout) {
  __shared__ char sA[NPB * 512];   // 32 KB
  const int tid = threadIdx.x;
  const int base = blockIdx.x * NPB;

#pragma unroll
  for (int i = 0; i < 8; ++i) {
    int c = tid + 256 * i;
    int row = c >> 5, kc = c & 31;
    int n = base + row;
    uint4 v = make_uint4(0, 0, 0, 0);
    if (n < N_NODES) {
      const bf16* sp = (kc < 16) ? (agg + (size_t)n * DIM + kc * 8)
                                 : (xb + (size_t)n * DIM + (kc - 16) * 8);
      v = *(const uint4*)sp;
    }
    int byte = (row * 512 + kc * 16) ^ ((row & 7) << 4);
    *(uint4*)(sA + byte) = v;
  }
  __syncthreads();

  const int w = tid >> 6, lane = tid & 63;
  const int j0 = w * 32;
  const int lrow = lane & 15, lk = lane >> 4;

  f32x4 acc[4][2];
#pragma unroll
  for (int mi = 0; mi < 4; ++mi)
#pragma unroll
    for (int ni = 0; ni < 2; ++ni)
      acc[mi][ni] = (f32x4){0.f, 0.f, 0.f, 0.f};

  for (int kt = 0; kt < 8; ++kt) {
    bfrag b0 = *(const bfrag*)(WT + (size_t)(j0 + lrow) * K2 + kt * 32 + lk * 8);
    bfrag b1 = *(const bfrag*)(WT + (size_t)(j0 + 16 + lrow) * K2 + kt * 32 + lk * 8);
#pragma unroll
    for (int mi = 0; mi < 4; ++mi) {
      int row = mi * 16 + lrow;
      int byte = (row * 512 + kt * 64 + lk * 16) ^ ((row & 7) << 4);
      bfrag a = *(const bfrag*)(sA + byte);
      acc[mi][0] = __builtin_amdgcn_mfma_f32_16x16x32_bf16(a, b0, acc[mi][0], 0, 0, 0);
      acc[mi][1] = __builtin_amdgcn_mfma_f32_16x16x32_bf16(a, b1, acc[mi][1], 0, 0, 0);
    }
  }

#pragma unroll
  for (int ni = 0; ni < 2; ++ni) {
    int colj = j0 + ni * 16 + lrow;
    float bv = bias[colj];
#pragma unroll
    for (int mi = 0; mi < 4; ++mi) {
#pragma unroll
      for (int r = 0; r < 4; ++r) {
        int n = base + mi * 16 + lk * 4 + r;
        if (n < N_NODES)
          hout[(size_t)n * DIM + colj] = __float2bfloat16(fmaxf(acc[mi][ni][r] + bv, 0.f));
      }
    }
  }
}

// ---------------- MFMA layer 1 + head ----------------
__global__ __launch_bounds__(256) void k_out(const bf16* __restrict__ agg,
                                             const bf16* __restrict__ xb,
                                             const bf16* __restrict__ WT,
                                             const float* __restrict__ bias,
                                             const bf16* __restrict__ WoT,
                                             const float* __restrict__ bo,
                                             float* __restrict__ out) {
  __shared__ char sA[NPB * 512];
  const int tid = threadIdx.x;
  const int base = blockIdx.x * NPB;

#pragma unroll
  for (int i = 0; i < 8; ++i) {
    int c = tid + 256 * i;
    int row = c >> 5, kc = c & 31;
    int n = base + row;
    uint4 v = make_uint4(0, 0, 0, 0);
    if (n < N_NODES) {
      const bf16* sp = (kc < 16) ? (agg + (size_t)n * DIM + kc * 8)
                                 : (xb + (size_t)n * DIM + (kc - 16) * 8);
      v = *(const uint4*)sp;
    }
    int byte = (row * 512 + kc * 16) ^ ((row & 7) << 4);
    *(uint4*)(sA + byte) = v;
  }
  __syncthreads();

  const int w = tid >> 6, lane = tid & 63;
  const int j0 = w * 32;
  const int lrow = lane & 15, lk = lane >> 4;

  f32x4 acc[4][2];
#pragma unroll
  for (int mi = 0; mi < 4; ++mi)
#pragma unroll
    for (int ni = 0; ni < 2; ++ni)
      acc[mi][ni] = (f32x4){0.f, 0.f, 0.f, 0.f};

  for (int kt = 0; kt < 8; ++kt) {
    bfrag b0 = *(const bfrag*)(WT + (size_t)(j0 + lrow) * K2 + kt * 32 + lk * 8);
    bfrag b1 = *(const bfrag*)(WT + (size_t)(j0 + 16 + lrow) * K2 + kt * 32 + lk * 8);
#pragma unroll
    for (int mi = 0; mi < 4; ++mi) {
      int row = mi * 16 + lrow;
      int byte = (row * 512 + kt * 64 + lk * 16) ^ ((row & 7) << 4);
      bfrag a = *(const bfrag*)(sA + byte);
      acc[mi][0] = __builtin_amdgcn_mfma_f32_16x16x32_bf16(a, b0, acc[mi][0], 0, 0, 0);
      acc[mi][1] = __builtin_amdgcn_mfma_f32_16x16x32_bf16(a, b1, acc[mi][1], 0, 0, 0);
    }
  }

  __syncthreads();
#pragma unroll
  for (int ni = 0; ni < 2; ++ni) {
    int colj = j0 + ni * 16 + lrow;
    float bv = bias[colj];
#pragma unroll
    for (int mi = 0; mi < 4; ++mi) {
#pragma unroll
      for (int r = 0; r < 4; ++r) {
        int row = mi * 16 + lk * 4 + r;
        float v = fmaxf(acc[mi][ni][r] + bv, 0.f);
        int byte = (row * 256 + colj * 2) ^ ((row & 7) << 4);
        *(bf16*)(sA + byte) = __float2bfloat16(v);
      }
    }
  }
  __syncthreads();

  const int jo = w * 16;
  f32x4 acc2[4];
#pragma unroll
  for (int mi = 0; mi < 4; ++mi) acc2[mi] = (f32x4){0.f, 0.f, 0.f, 0.f};

#pragma unroll
  for (int kt = 0; kt < 4; ++kt) {
    bfrag b = *(const bfrag*)(WoT + (size_t)(jo + lrow) * DIM + kt * 32 + lk * 8);
#pragma unroll
    for (int mi = 0; mi < 4; ++mi) {
      int row = mi * 16 + lrow;
      int byte = (row * 256 + kt * 64 + lk * 16) ^ ((row & 7) << 4);
      bfrag a = *(const bfrag*)(sA + byte);
      acc2[mi] = __builtin_amdgcn_mfma_f32_16x16x32_bf16(a, b, acc2[mi], 0, 0, 0);
    }
  }

  int colj = jo + lrow;
  float bv = bo[colj];
#pragma unroll
  for (int mi = 0; mi < 4; ++mi) {
#pragma unroll
    for (int r = 0; r < 4; ++r) {
      int n = base + mi * 16 + lk * 4 + r;
      if (n < N_NODES)
        out[(size_t)n * ODIM + colj] = 1.f / (1.f + __expf(-(acc2[mi][r] + bv)));
    }
  }
}

extern "C" void kernel_launch(void* const* d_in, const int* in_sizes, int n_in,
                              void* d_out, int out_size, void* d_ws, size_t ws_size,
                              hipStream_t stream) {
  const float* x     = (const float*)d_in[0];
  const int*   ei    = (const int*)d_in[1];
  const float* w_l0  = (const float*)d_in[2];
  const float* b_l0  = (const float*)d_in[3];
  const float* w_r0  = (const float*)d_in[4];
  const float* w_l1  = (const float*)d_in[5];
  const float* b_l1  = (const float*)d_in[6];
  const float* w_r1  = (const float*)d_in[7];
  const float* w_out = (const float*)d_in[8];
  const float* b_out = (const float*)d_in[9];
  float* out = (float*)d_out;

  const int* src = ei;
  const int* dst = ei + N_EDGES;

  char* ws = (char*)d_ws;
  int*      rowptr = (int*)(ws);                          // 400,004 B
  int*      gcur   = (int*)(ws + (512u << 10));           // 3,136 B
  int*      col    = (int*)(ws + (1u << 20));             // 6.4 MB (byte offsets)
  uint32_t* bdata  = (uint32_t*)(ws + (8u << 20));        // 8.03 MB (8 x 98 x 2560)
  bf16*     WT0    = (bf16*)(ws + (17u << 20));           // 64 KB
  bf16*     WT1    = (bf16*)(ws + (17u << 20) + 65536);   // 64 KB
  bf16*     WoT    = (bf16*)(ws + (17u << 20) + 131072);  // 16 KB
  bf16*     aggb   = (bf16*)(ws + (18ull << 20));         // 25.6 MB
  bf16*     h0b    = (bf16*)(ws + (44ull << 20));         // 25.6 MB
  bf16*     xb     = (bf16*)(ws + (70ull << 20));         // 25.6 MB (~95.6 MB total)

  // --- precompute (independent of CSR) ---
  k_cvt  <<<(N_NODES * DIM / 4 + 255) / 256, 256, 0, stream>>>(x, xb);
  k_prepw<<<(65536 + 8192 + 255) / 256, 256, 0, stream>>>(w_l0, w_r0, w_l1, w_r1, w_out,
                                                          WT0, WT1, WoT);

  // --- CSR build: block-binned bucket sort -> per-bucket CSR ---
  hipMemsetAsync(gcur, 0, NREP * CB * sizeof(int), stream);
  k_bucket<<<(N_EDGES + EPB - 1) / EPB, 1024, 0, stream>>>(src, dst, gcur, bdata);
  k_csr   <<<CB, 256, 0, stream>>>(bdata, gcur, rowptr, col);

  const int ablocks = (N_NODES * 64 + 255) / 256;
  const int gblocks = (N_NODES + NPB - 1) / NPB;

  // --- layer 0 ---
  k_agg <<<ablocks, 256, 0, stream>>>(xb, rowptr, col, aggb);
  k_sage<<<gblocks, 256, 0, stream>>>(aggb, xb, WT0, b_l0, h0b);

  // --- layer 1 + head ---
  k_agg<<<ablocks, 256, 0, stream>>>(h0b, rowptr, col, aggb);
  k_out<<<gblocks, 256, 0, stream>>>(aggb, h0b, WT1, b_l1, WoT, b_out, out);
}

// Round 10
// 238.804 us; speedup vs baseline: 1.1731x; 1.0485x over previous
//
#include <hip/hip_runtime.h>
#include <hip/hip_bf16.h>
#include <cstdint>

#define N_NODES 100000
#define N_EDGES 1600000
#define DIM 128
#define K2 256
#define ODIM 64
#define NPB 64
#define CB 98            // coarse buckets: dst>>10 (1024 nodes each)
#define NREP 8           // replicas (one per XCD via blockIdx&7 heuristic)
#define CAP1 2560        // per (rep,bucket) capacity: mean ~2048, +11 sigma
#define EPB 4096         // edges per k_bucket block

typedef __hip_bfloat16 bf16;
typedef __attribute__((ext_vector_type(8))) short bfrag;   // 8 bf16 = 4 VGPRs
typedef __attribute__((ext_vector_type(4))) float f32x4;
typedef __attribute__((ext_vector_type(2))) float f32x2;

// ---------------- bucket binning: LDS-sort 4096 edges by coarse key, bulk-append ----------------
__global__ __launch_bounds__(1024) void k_bucket(const int* __restrict__ src,
                                                 const int* __restrict__ dst,
                                                 int* __restrict__ gcur,
                                                 uint32_t* __restrict__ bdata) {
  __shared__ int hist[CB], hbase[CB], hcur[CB], gstart[CB];
  __shared__ uint32_t ent[EPB];
  __shared__ uint8_t kslot[EPB];
  const int tid = threadIdx.x;
  const int rep = blockIdx.x & (NREP - 1);
  const int e0 = blockIdx.x * EPB;
  const int cnt = min(EPB, N_EDGES - e0);

  if (tid < CB) { hist[tid] = 0; hcur[tid] = 0; }
  __syncthreads();

  const int me0 = e0 + tid * 4;
  int ss[4], dd[4];
  int nmine = max(0, min(4, N_EDGES - me0));
  if (nmine == 4) {
    *(int4*)ss = *(const int4*)(src + me0);
    *(int4*)dd = *(const int4*)(dst + me0);
  } else {
    for (int q = 0; q < nmine; ++q) { ss[q] = src[me0 + q]; dd[q] = dst[me0 + q]; }
  }

#pragma unroll
  for (int q = 0; q < 4; ++q)
    if (q < nmine) atomicAdd(&hist[dd[q] >> 10], 1);
  __syncthreads();

  if (tid == 0) {
    int run = 0;
    for (int b = 0; b < CB; ++b) { hbase[b] = run; run += hist[b]; }
  }
  __syncthreads();

#pragma unroll
  for (int q = 0; q < 4; ++q)
    if (q < nmine) {
      int key = dd[q] >> 10;
      int r = atomicAdd(&hcur[key], 1);
      int p = hbase[key] + r;
      ent[p] = ((uint32_t)ss[q] << 10) | (uint32_t)(dd[q] & 1023);
      kslot[p] = (uint8_t)key;
    }
  __syncthreads();

  if (tid < CB && hist[tid] > 0)
    gstart[tid] = atomicAdd(&gcur[rep * CB + tid], hist[tid]);
  __syncthreads();

  for (int i = tid; i < cnt; i += 1024) {
    int k = kslot[i];
    int pos = gstart[k] + (i - hbase[k]);
    if (pos < CAP1)
      bdata[((size_t)(rep * CB + k)) * CAP1 + pos] = ent[i];
  }
}

// ---------------- per-coarse-bucket CSR: 1024-node hist + scan + rank scatter ----------------
// col[] stores BYTE offsets (src * 128, fp8 rows) for the gather kernel.
__global__ __launch_bounds__(256) void k_csr(const uint32_t* __restrict__ bdata,
                                             const int* __restrict__ gcur,
                                             int* __restrict__ rowptr,
                                             int* __restrict__ col) {
  __shared__ int nc[1024], noff[1024];
  __shared__ int red[256];
  __shared__ int sz[NREP];
  const int b = blockIdx.x, tid = threadIdx.x;

  if (tid < NREP) sz[tid] = min(gcur[tid * CB + b], CAP1);

  int part = 0;
  for (int i = tid; i < NREP * b; i += 256) {
    int bp = i >> 3, r = i & 7;
    part += min(gcur[r * CB + bp], CAP1);
  }
  red[tid] = part;
  __syncthreads();
  for (int off = 128; off > 0; off >>= 1) {
    if (tid < off) red[tid] += red[tid + off];
    __syncthreads();
  }
  const int base = red[0];
  __syncthreads();

  for (int i = tid; i < 1024; i += 256) nc[i] = 0;
  __syncthreads();

  for (int r = 0; r < NREP; ++r) {
    int c = sz[r];
    const uint32_t* seg = bdata + ((size_t)(r * CB + b)) * CAP1;
    for (int i = tid; i < c; i += 256)
      atomicAdd(&nc[seg[i] & 1023], 1);
  }
  __syncthreads();

  int loc[4], s = 0;
#pragma unroll
  for (int q = 0; q < 4; ++q) { loc[q] = nc[tid * 4 + q]; s += loc[q]; }
  red[tid] = s;
  __syncthreads();
  for (int off = 1; off < 256; off <<= 1) {
    int add = (tid >= off) ? red[tid - off] : 0;
    __syncthreads();
    red[tid] += add;
    __syncthreads();
  }
  int p = red[tid] - s;
#pragma unroll
  for (int q = 0; q < 4; ++q) { noff[tid * 4 + q] = p; p += loc[q]; }
  __syncthreads();

  for (int i = tid; i < 1024; i += 256) {
    int n = b * 1024 + i;
    if (n < N_NODES) rowptr[n] = base + noff[i];
  }
  if (b == 0 && tid == 0) rowptr[N_NODES] = N_EDGES;

  for (int i = tid; i < 1024; i += 256) nc[i] = 0;
  __syncthreads();

  for (int r = 0; r < NREP; ++r) {
    int c = sz[r];
    const uint32_t* seg = bdata + ((size_t)(r * CB + b)) * CAP1;
    for (int i = tid; i < c; i += 256) {
      uint32_t e = seg[i];
      int n = e & 1023;
      int pos = atomicAdd(&nc[n], 1);
      col[base + noff[n] + pos] = (int)((e >> 10) << 7);   // byte offset: src * 128 (fp8)
    }
  }
}

// ---------------- precompute: x -> bf16 + fp8 ----------------
__global__ __launch_bounds__(256) void k_cvt(const float* __restrict__ x,
                                             bf16* __restrict__ xb,
                                             uint8_t* __restrict__ x8) {
  int i = (blockIdx.x * 256 + threadIdx.x) * 4;
  if (i >= N_NODES * DIM) return;
  float4 v = *(const float4*)(x + i);
  bf16 t[4];
  t[0] = __float2bfloat16(v.x);
  t[1] = __float2bfloat16(v.y);
  t[2] = __float2bfloat16(v.z);
  t[3] = __float2bfloat16(v.w);
  *(uint2*)(xb + i) = *(uint2*)t;
  int p8 = __builtin_amdgcn_cvt_pk_fp8_f32(v.x, v.y, 0, false);
  p8 = __builtin_amdgcn_cvt_pk_fp8_f32(v.z, v.w, p8, true);
  *(int*)(x8 + i) = p8;
}

// ---------------- h0 bf16 -> fp8 ----------------
__global__ __launch_bounds__(256) void k_cvt8(const bf16* __restrict__ h,
                                              uint8_t* __restrict__ h8) {
  int i = (blockIdx.x * 256 + threadIdx.x) * 8;
  if (i >= N_NODES * DIM) return;
  uint4 v = *(const uint4*)(h + i);
  uint32_t ws[4] = {v.x, v.y, v.z, v.w};
  float f[8];
#pragma unroll
  for (int q = 0; q < 4; ++q) {
    f[2 * q]     = __uint_as_float(ws[q] << 16);
    f[2 * q + 1] = __uint_as_float(ws[q] & 0xFFFF0000u);
  }
  int lo = __builtin_amdgcn_cvt_pk_fp8_f32(f[0], f[1], 0, false);
  lo = __builtin_amdgcn_cvt_pk_fp8_f32(f[2], f[3], lo, true);
  int hi = __builtin_amdgcn_cvt_pk_fp8_f32(f[4], f[5], 0, false);
  hi = __builtin_amdgcn_cvt_pk_fp8_f32(f[6], f[7], hi, true);
  uint2 o; o.x = (uint32_t)lo; o.y = (uint32_t)hi;
  *(uint2*)(h8 + i) = o;
}

// ---------------- precompute: pack weights transposed bf16 ----------------
__global__ __launch_bounds__(256) void k_prepw(const float* __restrict__ wl0,
                                               const float* __restrict__ wr0,
                                               const float* __restrict__ wl1,
                                               const float* __restrict__ wr1,
                                               const float* __restrict__ wo,
                                               bf16* __restrict__ WT0,
                                               bf16* __restrict__ WT1,
                                               bf16* __restrict__ WoT) {
  int g = blockIdx.x * 256 + threadIdx.x;
  if (g < 32768) {
    int j = g >> 8, k = g & 255;
    float v = (k < DIM) ? wl0[k * DIM + j] : wr0[(k - DIM) * DIM + j];
    WT0[g] = __float2bfloat16(v);
  } else if (g < 65536) {
    int gg = g - 32768;
    int j = gg >> 8, k = gg & 255;
    float v = (k < DIM) ? wl1[k * DIM + j] : wr1[(k - DIM) * DIM + j];
    WT1[gg] = __float2bfloat16(v);
  } else if (g < 65536 + 8192) {
    int gg = g - 65536;
    int j = gg >> 7, k = gg & 127;
    WoT[gg] = __float2bfloat16(wo[k * ODIM + j]);
  }
}

// ---------------- pull aggregation (fp8 rows, 128B): 1 wave/node, 16 edges in flight ----------------
__device__ __forceinline__ void accv8(f32x2* acc, uint2 v) {
  f32x2 t0 = __builtin_amdgcn_cvt_pk_f32_fp8(v.x, false);
  f32x2 t1 = __builtin_amdgcn_cvt_pk_f32_fp8(v.x, true);
  f32x2 t2 = __builtin_amdgcn_cvt_pk_f32_fp8(v.y, false);
  f32x2 t3 = __builtin_amdgcn_cvt_pk_f32_fp8(v.y, true);
  acc[0] += t0; acc[1] += t1; acc[2] += t2; acc[3] += t3;
}

__global__ __launch_bounds__(256) void k_agg(const uint8_t* __restrict__ feat8,
                                             const int* __restrict__ rowptr,
                                             const int* __restrict__ colb,
                                             bf16* __restrict__ agg) {
  int gid = blockIdx.x * 256 + threadIdx.x;
  int node = gid >> 6;
  if (node >= N_NODES) return;
  int lane = gid & 63;
  int g = lane >> 4, lg = lane & 15;
  int beg = rowptr[node], end = rowptr[node + 1];
  const char* fb = (const char*)feat8 + lg * 8;

  f32x2 acc[4];
#pragma unroll
  for (int q = 0; q < 4; ++q) acc[q] = (f32x2){0.f, 0.f};

  int j = beg;
  // 16 edges in flight (4 groups x 4-deep)
  for (; j + 16 <= end; j += 16) {
    int o0 = colb[j + g];
    int o1 = colb[j + 4 + g];
    int o2 = colb[j + 8 + g];
    int o3 = colb[j + 12 + g];
    uint2 v0 = *(const uint2*)(fb + o0);
    uint2 v1 = *(const uint2*)(fb + o1);
    uint2 v2 = *(const uint2*)(fb + o2);
    uint2 v3 = *(const uint2*)(fb + o3);
    accv8(acc, v0); accv8(acc, v1); accv8(acc, v2); accv8(acc, v3);
  }
  for (; j + 4 <= end; j += 4) {
    int o = colb[j + g];
    uint2 v = *(const uint2*)(fb + o);
    accv8(acc, v);
  }
  int rem = end - j;
  if (g < rem) {
    int o = colb[j + g];
    uint2 v = *(const uint2*)(fb + o);
    accv8(acc, v);
  }

  // reduce across the 4 edge groups
#pragma unroll
  for (int q = 0; q < 4; ++q) {
#pragma unroll
    for (int c = 0; c < 2; ++c) {
      acc[q][c] += __shfl_xor(acc[q][c], 16, 64);
      acc[q][c] += __shfl_xor(acc[q][c], 32, 64);
    }
  }

  if (g == 0) {
    float inv = (end > beg) ? 1.0f / (float)(end - beg) : 0.f;
    union { uint32_t u[4]; uint4 v; } o;
#pragma unroll
    for (int q = 0; q < 4; ++q) {
      __hip_bfloat162 h;
      h.x = __float2bfloat16(acc[q][0] * inv);
      h.y = __float2bfloat16(acc[q][1] * inv);
      o.u[q] = *(uint32_t*)&h;
    }
    *(uint4*)(agg + (size_t)node * DIM + lg * 8) = o.v;
  }
}

// ---------------- MFMA SAGE layer: h = relu([agg|x] @ WT^T + b) ----------------
__global__ __launch_bounds__(256) void k_sage(const bf16* __restrict__ agg,
                                              const bf16* __restrict__ xb,
                                              const bf16* __restrict__ WT,
                                              const float* __restrict__ bias,
                                              bf16* __restrict__ hout) {
  __shared__ char sA[NPB * 512];   // 32 KB
  const int tid = threadIdx.x;
  const int base = blockIdx.x * NPB;

#pragma unroll
  for (int i = 0; i < 8; ++i) {
    int c = tid + 256 * i;
    int row = c >> 5, kc = c & 31;
    int n = base + row;
    uint4 v = make_uint4(0, 0, 0, 0);
    if (n < N_NODES) {
      const bf16* sp = (kc < 16) ? (agg + (size_t)n * DIM + kc * 8)
                                 : (xb + (size_t)n * DIM + (kc - 16) * 8);
      v = *(const uint4*)sp;
    }
    int byte = (row * 512 + kc * 16) ^ ((row & 7) << 4);
    *(uint4*)(sA + byte) = v;
  }
  __syncthreads();

  const int w = tid >> 6, lane = tid & 63;
  const int j0 = w * 32;
  const int lrow = lane & 15, lk = lane >> 4;

  f32x4 acc[4][2];
#pragma unroll
  for (int mi = 0; mi < 4; ++mi)
#pragma unroll
    for (int ni = 0; ni < 2; ++ni)
      acc[mi][ni] = (f32x4){0.f, 0.f, 0.f, 0.f};

  for (int kt = 0; kt < 8; ++kt) {
    bfrag b0 = *(const bfrag*)(WT + (size_t)(j0 + lrow) * K2 + kt * 32 + lk * 8);
    bfrag b1 = *(const bfrag*)(WT + (size_t)(j0 + 16 + lrow) * K2 + kt * 32 + lk * 8);
#pragma unroll
    for (int mi = 0; mi < 4; ++mi) {
      int row = mi * 16 + lrow;
      int byte = (row * 512 + kt * 64 + lk * 16) ^ ((row & 7) << 4);
      bfrag a = *(const bfrag*)(sA + byte);
      acc[mi][0] = __builtin_amdgcn_mfma_f32_16x16x32_bf16(a, b0, acc[mi][0], 0, 0, 0);
      acc[mi][1] = __builtin_amdgcn_mfma_f32_16x16x32_bf16(a, b1, acc[mi][1], 0, 0, 0);
    }
  }

#pragma unroll
  for (int ni = 0; ni < 2; ++ni) {
    int colj = j0 + ni * 16 + lrow;
    float bv = bias[colj];
#pragma unroll
    for (int mi = 0; mi < 4; ++mi) {
#pragma unroll
      for (int r = 0; r < 4; ++r) {
        int n = base + mi * 16 + lk * 4 + r;
        if (n < N_NODES)
          hout[(size_t)n * DIM + colj] = __float2bfloat16(fmaxf(acc[mi][ni][r] + bv, 0.f));
      }
    }
  }
}

// ---------------- MFMA layer 1 + head ----------------
__global__ __launch_bounds__(256) void k_out(const bf16* __restrict__ agg,
                                             const bf16* __restrict__ xb,
                                             const bf16* __restrict__ WT,
                                             const float* __restrict__ bias,
                                             const bf16* __restrict__ WoT,
                                             const float* __restrict__ bo,
                                             float* __restrict__ out) {
  __shared__ char sA[NPB * 512];
  const int tid = threadIdx.x;
  const int base = blockIdx.x * NPB;

#pragma unroll
  for (int i = 0; i < 8; ++i) {
    int c = tid + 256 * i;
    int row = c >> 5, kc = c & 31;
    int n = base + row;
    uint4 v = make_uint4(0, 0, 0, 0);
    if (n < N_NODES) {
      const bf16* sp = (kc < 16) ? (agg + (size_t)n * DIM + kc * 8)
                                 : (xb + (size_t)n * DIM + (kc - 16) * 8);
      v = *(const uint4*)sp;
    }
    int byte = (row * 512 + kc * 16) ^ ((row & 7) << 4);
    *(uint4*)(sA + byte) = v;
  }
  __syncthreads();

  const int w = tid >> 6, lane = tid & 63;
  const int j0 = w * 32;
  const int lrow = lane & 15, lk = lane >> 4;

  f32x4 acc[4][2];
#pragma unroll
  for (int mi = 0; mi < 4; ++mi)
#pragma unroll
    for (int ni = 0; ni < 2; ++ni)
      acc[mi][ni] = (f32x4){0.f, 0.f, 0.f, 0.f};

  for (int kt = 0; kt < 8; ++kt) {
    bfrag b0 = *(const bfrag*)(WT + (size_t)(j0 + lrow) * K2 + kt * 32 + lk * 8);
    bfrag b1 = *(const bfrag*)(WT + (size_t)(j0 + 16 + lrow) * K2 + kt * 32 + lk * 8);
#pragma unroll
    for (int mi = 0; mi < 4; ++mi) {
      int row = mi * 16 + lrow;
      int byte = (row * 512 + kt * 64 + lk * 16) ^ ((row & 7) << 4);
      bfrag a = *(const bfrag*)(sA + byte);
      acc[mi][0] = __builtin_amdgcn_mfma_f32_16x16x32_bf16(a, b0, acc[mi][0], 0, 0, 0);
      acc[mi][1] = __builtin_amdgcn_mfma_f32_16x16x32_bf16(a, b1, acc[mi][1], 0, 0, 0);
    }
  }

  __syncthreads();
#pragma unroll
  for (int ni = 0; ni < 2; ++ni) {
    int colj = j0 + ni * 16 + lrow;
    float bv = bias[colj];
#pragma unroll
    for (int mi = 0; mi < 4; ++mi) {
#pragma unroll
      for (int r = 0; r < 4; ++r) {
        int row = mi * 16 + lk * 4 + r;
        float v = fmaxf(acc[mi][ni][r] + bv, 0.f);
        int byte = (row * 256 + colj * 2) ^ ((row & 7) << 4);
        *(bf16*)(sA + byte) = __float2bfloat16(v);
      }
    }
  }
  __syncthreads();

  const int jo = w * 16;
  f32x4 acc2[4];
#pragma unroll
  for (int mi = 0; mi < 4; ++mi) acc2[mi] = (f32x4){0.f, 0.f, 0.f, 0.f};

#pragma unroll
  for (int kt = 0; kt < 4; ++kt) {
    bfrag b = *(const bfrag*)(WoT + (size_t)(jo + lrow) * DIM + kt * 32 + lk * 8);
#pragma unroll
    for (int mi = 0; mi < 4; ++mi) {
      int row = mi * 16 + lrow;
      int byte = (row * 256 + kt * 64 + lk * 16) ^ ((row & 7) << 4);
      bfrag a = *(const bfrag*)(sA + byte);
      acc2[mi] = __builtin_amdgcn_mfma_f32_16x16x32_bf16(a, b, acc2[mi], 0, 0, 0);
    }
  }

  int colj = jo + lrow;
  float bv = bo[colj];
#pragma unroll
  for (int mi = 0; mi < 4; ++mi) {
#pragma unroll
    for (int r = 0; r < 4; ++r) {
      int n = base + mi * 16 + lk * 4 + r;
      if (n < N_NODES)
        out[(size_t)n * ODIM + colj] = 1.f / (1.f + __expf(-(acc2[mi][r] + bv)));
    }
  }
}

extern "C" void kernel_launch(void* const* d_in, const int* in_sizes, int n_in,
                              void* d_out, int out_size, void* d_ws, size_t ws_size,
                              hipStream_t stream) {
  const float* x     = (const float*)d_in[0];
  const int*   ei    = (const int*)d_in[1];
  const float* w_l0  = (const float*)d_in[2];
  const float* b_l0  = (const float*)d_in[3];
  const float* w_r0  = (const float*)d_in[4];
  const float* w_l1  = (const float*)d_in[5];
  const float* b_l1  = (const float*)d_in[6];
  const float* w_r1  = (const float*)d_in[7];
  const float* w_out = (const float*)d_in[8];
  const float* b_out = (const float*)d_in[9];
  float* out = (float*)d_out;

  const int* src = ei;
  const int* dst = ei + N_EDGES;

  char* ws = (char*)d_ws;
  int*      rowptr = (int*)(ws);                          // 400,004 B
  int*      gcur   = (int*)(ws + (512u << 10));           // 3,136 B
  int*      col    = (int*)(ws + (1u << 20));             // 6.4 MB (byte offsets)
  uint32_t* bdata  = (uint32_t*)(ws + (8u << 20));        // 8.03 MB (dead after k_csr)
  uint8_t*  x8     = (uint8_t*)(ws + (8u << 20));         // 12.8 MB (overlays bdata; after CSR)
  uint8_t*  h08    = (uint8_t*)(ws + (8u << 20));         // 12.8 MB (overlays x8; after layer 0)
  bf16*     WT0    = (bf16*)(ws + (21u << 20));           // 64 KB
  bf16*     WT1    = (bf16*)(ws + (21u << 20) + 65536);   // 64 KB
  bf16*     WoT    = (bf16*)(ws + (21u << 20) + 131072);  // 16 KB
  bf16*     aggb   = (bf16*)(ws + (22ull << 20));         // 25.6 MB
  bf16*     h0b    = (bf16*)(ws + (48ull << 20));         // 25.6 MB
  bf16*     xb     = (bf16*)(ws + (74ull << 20));         // 25.6 MB (~99.6 MB total)

  // --- CSR build first (bdata region is then reused for fp8 tables) ---
  hipMemsetAsync(gcur, 0, NREP * CB * sizeof(int), stream);
  k_bucket<<<(N_EDGES + EPB - 1) / EPB, 1024, 0, stream>>>(src, dst, gcur, bdata);
  k_csr   <<<CB, 256, 0, stream>>>(bdata, gcur, rowptr, col);

  // --- precompute (x -> bf16 + fp8; weights) ---
  k_cvt  <<<(N_NODES * DIM / 4 + 255) / 256, 256, 0, stream>>>(x, xb, x8);
  k_prepw<<<(65536 + 8192 + 255) / 256, 256, 0, stream>>>(w_l0, w_r0, w_l1, w_r1, w_out,
                                                          WT0, WT1, WoT);

  const int ablocks = (N_NODES * 64 + 255) / 256;
  const int gblocks = (N_NODES + NPB - 1) / NPB;

  // --- layer 0 ---
  k_agg <<<ablocks, 256, 0, stream>>>(x8, rowptr, col, aggb);
  k_sage<<<gblocks, 256, 0, stream>>>(aggb, xb, WT0, b_l0, h0b);

  // --- layer 1 + head ---
  k_cvt8<<<(N_NODES * DIM / 8 + 255) / 256, 256, 0, stream>>>(h0b, h08);
  k_agg <<<ablocks, 256, 0, stream>>>(h08, rowptr, col, aggb);
  k_out <<<gblocks, 256, 0, stream>>>(aggb, h0b, WT1, b_l1, WoT, b_out, out);
}

// Round 11
// 233.234 us; speedup vs baseline: 1.2011x; 1.0239x over previous
//
#include <hip/hip_runtime.h>
#include <hip/hip_bf16.h>
#include <cstdint>

#define N_NODES 100000
#define N_EDGES 1600000
#define DIM 128
#define K2 256
#define ODIM 64
#define NPB 64
#define CB 98            // coarse buckets: dst>>10 (1024 nodes each)
#define NREP 8           // replicas (one per XCD via blockIdx&7 heuristic)
#define CAP1 2560        // per (rep,bucket) capacity: mean ~2048, +11 sigma
#define EPB 4096         // edges per k_bucket block
#define NWAVE 16         // waves per k_bucket block

typedef __hip_bfloat16 bf16;
typedef __attribute__((ext_vector_type(8))) short bfrag;   // 8 bf16 = 4 VGPRs
typedef __attribute__((ext_vector_type(4))) float f32x4;
typedef __attribute__((ext_vector_type(2))) float f32x2;

__device__ __forceinline__ void gload16(const void* g, void* l) {
  __builtin_amdgcn_global_load_lds((const __attribute__((address_space(1))) void*)g,
                                   (__attribute__((address_space(3))) void*)l, 16, 0, 0);
}

// ---------------- bucket binning: per-wave hist + LDS-sort, bulk-append ----------------
__global__ __launch_bounds__(1024) void k_bucket(const int* __restrict__ src,
                                                 const int* __restrict__ dst,
                                                 int* __restrict__ gcur,
                                                 uint32_t* __restrict__ bdata) {
  __shared__ int wh[NWAVE][CB];    // per-wave counts -> per-wave start offsets
  __shared__ int wcur[NWAVE][CB];  // per-wave cursors
  __shared__ int hist[CB], hbase[CB], gstart[CB];
  __shared__ uint32_t ent[EPB];
  __shared__ uint8_t kslot[EPB];
  const int tid = threadIdx.x;
  const int wave = tid >> 6;
  const int rep = blockIdx.x & (NREP - 1);
  const int e0 = blockIdx.x * EPB;
  const int cnt = min(EPB, N_EDGES - e0);

  for (int i = tid; i < NWAVE * CB; i += 1024) {
    ((int*)wh)[i] = 0;
    ((int*)wcur)[i] = 0;
  }
  __syncthreads();

  const int me0 = e0 + tid * 4;
  int ss[4], dd[4];
  int nmine = max(0, min(4, N_EDGES - me0));
  if (nmine == 4) {
    *(int4*)ss = *(const int4*)(src + me0);
    *(int4*)dd = *(const int4*)(dst + me0);
  } else {
    for (int q = 0; q < nmine; ++q) { ss[q] = src[me0 + q]; dd[q] = dst[me0 + q]; }
  }

#pragma unroll
  for (int q = 0; q < 4; ++q)
    if (q < nmine) atomicAdd(&wh[wave][dd[q] >> 10], 1);
  __syncthreads();

  // per-bucket: totals + per-wave start offsets (wh[w][b] becomes wave w's offset)
  if (tid < CB) {
    int run = 0;
#pragma unroll
    for (int w = 0; w < NWAVE; ++w) {
      int c = wh[w][tid];
      wh[w][tid] = run;
      run += c;
    }
    hist[tid] = run;
  }
  __syncthreads();

  if (tid == 0) {
    int run = 0;
    for (int b = 0; b < CB; ++b) { hbase[b] = run; run += hist[b]; }
  }
  __syncthreads();

#pragma unroll
  for (int q = 0; q < 4; ++q)
    if (q < nmine) {
      int key = dd[q] >> 10;
      int r = atomicAdd(&wcur[wave][key], 1);
      int p = hbase[key] + wh[wave][key] + r;
      ent[p] = ((uint32_t)ss[q] << 10) | (uint32_t)(dd[q] & 1023);
      kslot[p] = (uint8_t)key;
    }
  __syncthreads();

  if (tid < CB && hist[tid] > 0)
    gstart[tid] = atomicAdd(&gcur[rep * CB + tid], hist[tid]);
  __syncthreads();

  for (int i = tid; i < cnt; i += 1024) {
    int k = kslot[i];
    int pos = gstart[k] + (i - hbase[k]);
    if (pos < CAP1)
      bdata[((size_t)(rep * CB + k)) * CAP1 + pos] = ent[i];
  }
}

// ---------------- per-coarse-bucket CSR: 1024-node hist + scan + rank scatter ----------------
// col[] stores BYTE offsets (src * 128, fp8 rows) for the gather kernel.
__global__ __launch_bounds__(256) void k_csr(const uint32_t* __restrict__ bdata,
                                             const int* __restrict__ gcur,
                                             int* __restrict__ rowptr,
                                             int* __restrict__ col) {
  __shared__ int nc[1024], noff[1024];
  __shared__ int red[256];
  __shared__ int sz[NREP];
  const int b = blockIdx.x, tid = threadIdx.x;

  if (tid < NREP) sz[tid] = min(gcur[tid * CB + b], CAP1);

  int part = 0;
  for (int i = tid; i < NREP * b; i += 256) {
    int bp = i >> 3, r = i & 7;
    part += min(gcur[r * CB + bp], CAP1);
  }
  red[tid] = part;
  __syncthreads();
  for (int off = 128; off > 0; off >>= 1) {
    if (tid < off) red[tid] += red[tid + off];
    __syncthreads();
  }
  const int base = red[0];
  __syncthreads();

  for (int i = tid; i < 1024; i += 256) nc[i] = 0;
  __syncthreads();

  for (int r = 0; r < NREP; ++r) {
    int c = sz[r];
    const uint32_t* seg = bdata + ((size_t)(r * CB + b)) * CAP1;
    for (int i = tid; i < c; i += 256)
      atomicAdd(&nc[seg[i] & 1023], 1);
  }
  __syncthreads();

  int loc[4], s = 0;
#pragma unroll
  for (int q = 0; q < 4; ++q) { loc[q] = nc[tid * 4 + q]; s += loc[q]; }
  red[tid] = s;
  __syncthreads();
  for (int off = 1; off < 256; off <<= 1) {
    int add = (tid >= off) ? red[tid - off] : 0;
    __syncthreads();
    red[tid] += add;
    __syncthreads();
  }
  int p = red[tid] - s;
#pragma unroll
  for (int q = 0; q < 4; ++q) { noff[tid * 4 + q] = p; p += loc[q]; }
  __syncthreads();

  for (int i = tid; i < 1024; i += 256) {
    int n = b * 1024 + i;
    if (n < N_NODES) rowptr[n] = base + noff[i];
  }
  if (b == 0 && tid == 0) rowptr[N_NODES] = N_EDGES;

  for (int i = tid; i < 1024; i += 256) nc[i] = 0;
  __syncthreads();

  for (int r = 0; r < NREP; ++r) {
    int c = sz[r];
    const uint32_t* seg = bdata + ((size_t)(r * CB + b)) * CAP1;
    for (int i = tid; i < c; i += 256) {
      uint32_t e = seg[i];
      int n = e & 1023;
      int pos = atomicAdd(&nc[n], 1);
      col[base + noff[n] + pos] = (int)((e >> 10) << 7);   // byte offset: src * 128 (fp8)
    }
  }
}

// ---------------- precompute: x -> bf16 + fp8 ----------------
__global__ __launch_bounds__(256) void k_cvt(const float* __restrict__ x,
                                             bf16* __restrict__ xb,
                                             uint8_t* __restrict__ x8) {
  int i = (blockIdx.x * 256 + threadIdx.x) * 4;
  if (i >= N_NODES * DIM) return;
  float4 v = *(const float4*)(x + i);
  bf16 t[4];
  t[0] = __float2bfloat16(v.x);
  t[1] = __float2bfloat16(v.y);
  t[2] = __float2bfloat16(v.z);
  t[3] = __float2bfloat16(v.w);
  *(uint2*)(xb + i) = *(uint2*)t;
  int p8 = __builtin_amdgcn_cvt_pk_fp8_f32(v.x, v.y, 0, false);
  p8 = __builtin_amdgcn_cvt_pk_fp8_f32(v.z, v.w, p8, true);
  *(int*)(x8 + i) = p8;
}

// ---------------- precompute: pack weights transposed bf16 ----------------
__global__ __launch_bounds__(256) void k_prepw(const float* __restrict__ wl0,
                                               const float* __restrict__ wr0,
                                               const float* __restrict__ wl1,
                                               const float* __restrict__ wr1,
                                               const float* __restrict__ wo,
                                               bf16* __restrict__ WT0,
                                               bf16* __restrict__ WT1,
                                               bf16* __restrict__ WoT) {
  int g = blockIdx.x * 256 + threadIdx.x;
  if (g < 32768) {
    int j = g >> 8, k = g & 255;
    float v = (k < DIM) ? wl0[k * DIM + j] : wr0[(k - DIM) * DIM + j];
    WT0[g] = __float2bfloat16(v);
  } else if (g < 65536) {
    int gg = g - 32768;
    int j = gg >> 8, k = gg & 255;
    float v = (k < DIM) ? wl1[k * DIM + j] : wr1[(k - DIM) * DIM + j];
    WT1[gg] = __float2bfloat16(v);
  } else if (g < 65536 + 8192) {
    int gg = g - 65536;
    int j = gg >> 7, k = gg & 127;
    WoT[gg] = __float2bfloat16(wo[k * ODIM + j]);
  }
}

// ---------------- pull aggregation (fp8 rows, 128B): 1 wave/node, 16 edges in flight ----------------
__device__ __forceinline__ void accv8(f32x2* acc, uint2 v) {
  f32x2 t0 = __builtin_amdgcn_cvt_pk_f32_fp8(v.x, false);
  f32x2 t1 = __builtin_amdgcn_cvt_pk_f32_fp8(v.x, true);
  f32x2 t2 = __builtin_amdgcn_cvt_pk_f32_fp8(v.y, false);
  f32x2 t3 = __builtin_amdgcn_cvt_pk_f32_fp8(v.y, true);
  acc[0] += t0; acc[1] += t1; acc[2] += t2; acc[3] += t3;
}

__global__ __launch_bounds__(256) void k_agg(const uint8_t* __restrict__ feat8,
                                             const int* __restrict__ rowptr,
                                             const int* __restrict__ colb,
                                             bf16* __restrict__ agg) {
  int gid = blockIdx.x * 256 + threadIdx.x;
  int node = gid >> 6;
  if (node >= N_NODES) return;
  int lane = gid & 63;
  int g = lane >> 4, lg = lane & 15;
  int beg = rowptr[node], end = rowptr[node + 1];
  const char* fb = (const char*)feat8 + lg * 8;

  f32x2 acc[4];
#pragma unroll
  for (int q = 0; q < 4; ++q) acc[q] = (f32x2){0.f, 0.f};

  int j = beg;
  for (; j + 16 <= end; j += 16) {
    int o0 = colb[j + g];
    int o1 = colb[j + 4 + g];
    int o2 = colb[j + 8 + g];
    int o3 = colb[j + 12 + g];
    uint2 v0 = *(const uint2*)(fb + o0);
    uint2 v1 = *(const uint2*)(fb + o1);
    uint2 v2 = *(const uint2*)(fb + o2);
    uint2 v3 = *(const uint2*)(fb + o3);
    accv8(acc, v0); accv8(acc, v1); accv8(acc, v2); accv8(acc, v3);
  }
  for (; j + 4 <= end; j += 4) {
    int o = colb[j + g];
    uint2 v = *(const uint2*)(fb + o);
    accv8(acc, v);
  }
  int rem = end - j;
  if (g < rem) {
    int o = colb[j + g];
    uint2 v = *(const uint2*)(fb + o);
    accv8(acc, v);
  }

#pragma unroll
  for (int q = 0; q < 4; ++q) {
#pragma unroll
    for (int c = 0; c < 2; ++c) {
      acc[q][c] += __shfl_xor(acc[q][c], 16, 64);
      acc[q][c] += __shfl_xor(acc[q][c], 32, 64);
    }
  }

  if (g == 0) {
    float inv = (end > beg) ? 1.0f / (float)(end - beg) : 0.f;
    union { uint32_t u[4]; uint4 v; } o;
#pragma unroll
    for (int q = 0; q < 4; ++q) {
      __hip_bfloat162 h;
      h.x = __float2bfloat16(acc[q][0] * inv);
      h.y = __float2bfloat16(acc[q][1] * inv);
      o.u[q] = *(uint32_t*)&h;
    }
    *(uint4*)(agg + (size_t)node * DIM + lg * 8) = o.v;
  }
}

// ---------------- MFMA SAGE layer: h = relu([agg|x] @ WT^T + b), writes bf16 + fp8 ----------------
// A-tile staged via global_load_lds: LINEAR LDS dest, inverse-swizzled per-lane source
// (slot c holds logical chunk kc^(row&7); read path applies the same XOR -> identity).
__global__ __launch_bounds__(256) void k_sage(const bf16* __restrict__ agg,
                                              const bf16* __restrict__ xb,
                                              const bf16* __restrict__ WT,
                                              const float* __restrict__ bias,
                                              bf16* __restrict__ hout,
                                              uint8_t* __restrict__ h8) {
  __shared__ char sA[NPB * 512];   // 32 KB
  const int tid = threadIdx.x;
  const int base = blockIdx.x * NPB;

#pragma unroll
  for (int i = 0; i < 8; ++i) {
    int c = tid + 256 * i;                 // chunk 0..2047 (16B each)
    int row = c >> 5;
    int n = min(base + row, N_NODES - 1);  // clamp: garbage rows feed guarded outputs only
    int kcg = (c & 31) ^ (row & 7);        // inverse-swizzled logical chunk
    const bf16* sp = (kcg < 16) ? (agg + (size_t)n * DIM + kcg * 8)
                                : (xb + (size_t)n * DIM + (kcg - 16) * 8);
    gload16(sp, sA + c * 16);
  }
  __syncthreads();

  const int w = tid >> 6, lane = tid & 63;
  const int j0 = w * 32;
  const int lrow = lane & 15, lk = lane >> 4;

  f32x4 acc[4][2];
#pragma unroll
  for (int mi = 0; mi < 4; ++mi)
#pragma unroll
    for (int ni = 0; ni < 2; ++ni)
      acc[mi][ni] = (f32x4){0.f, 0.f, 0.f, 0.f};

  for (int kt = 0; kt < 8; ++kt) {
    bfrag b0 = *(const bfrag*)(WT + (size_t)(j0 + lrow) * K2 + kt * 32 + lk * 8);
    bfrag b1 = *(const bfrag*)(WT + (size_t)(j0 + 16 + lrow) * K2 + kt * 32 + lk * 8);
#pragma unroll
    for (int mi = 0; mi < 4; ++mi) {
      int row = mi * 16 + lrow;
      int byte = (row * 512 + kt * 64 + lk * 16) ^ ((row & 7) << 4);
      bfrag a = *(const bfrag*)(sA + byte);
      acc[mi][0] = __builtin_amdgcn_mfma_f32_16x16x32_bf16(a, b0, acc[mi][0], 0, 0, 0);
      acc[mi][1] = __builtin_amdgcn_mfma_f32_16x16x32_bf16(a, b1, acc[mi][1], 0, 0, 0);
    }
  }

#pragma unroll
  for (int ni = 0; ni < 2; ++ni) {
    int colj = j0 + ni * 16 + lrow;
    float bv = bias[colj];
#pragma unroll
    for (int mi = 0; mi < 4; ++mi) {
#pragma unroll
      for (int r = 0; r < 4; ++r) {
        int n = base + mi * 16 + lk * 4 + r;
        if (n < N_NODES) {
          float v = fmaxf(acc[mi][ni][r] + bv, 0.f);
          hout[(size_t)n * DIM + colj] = __float2bfloat16(v);
          h8[(size_t)n * DIM + colj] =
              (uint8_t)(__builtin_amdgcn_cvt_pk_fp8_f32(v, v, 0, false) & 0xFF);
        }
      }
    }
  }
}

// ---------------- MFMA layer 1 + head ----------------
__global__ __launch_bounds__(256) void k_out(const bf16* __restrict__ agg,
                                             const bf16* __restrict__ xb,
                                             const bf16* __restrict__ WT,
                                             const float* __restrict__ bias,
                                             const bf16* __restrict__ WoT,
                                             const float* __restrict__ bo,
                                             float* __restrict__ out) {
  __shared__ char sA[NPB * 512];
  const int tid = threadIdx.x;
  const int base = blockIdx.x * NPB;

#pragma unroll
  for (int i = 0; i < 8; ++i) {
    int c = tid + 256 * i;
    int row = c >> 5;
    int n = min(base + row, N_NODES - 1);
    int kcg = (c & 31) ^ (row & 7);
    const bf16* sp = (kcg < 16) ? (agg + (size_t)n * DIM + kcg * 8)
                                : (xb + (size_t)n * DIM + (kcg - 16) * 8);
    gload16(sp, sA + c * 16);
  }
  __syncthreads();

  const int w = tid >> 6, lane = tid & 63;
  const int j0 = w * 32;
  const int lrow = lane & 15, lk = lane >> 4;

  f32x4 acc[4][2];
#pragma unroll
  for (int mi = 0; mi < 4; ++mi)
#pragma unroll
    for (int ni = 0; ni < 2; ++ni)
      acc[mi][ni] = (f32x4){0.f, 0.f, 0.f, 0.f};

  for (int kt = 0; kt < 8; ++kt) {
    bfrag b0 = *(const bfrag*)(WT + (size_t)(j0 + lrow) * K2 + kt * 32 + lk * 8);
    bfrag b1 = *(const bfrag*)(WT + (size_t)(j0 + 16 + lrow) * K2 + kt * 32 + lk * 8);
#pragma unroll
    for (int mi = 0; mi < 4; ++mi) {
      int row = mi * 16 + lrow;
      int byte = (row * 512 + kt * 64 + lk * 16) ^ ((row & 7) << 4);
      bfrag a = *(const bfrag*)(sA + byte);
      acc[mi][0] = __builtin_amdgcn_mfma_f32_16x16x32_bf16(a, b0, acc[mi][0], 0, 0, 0);
      acc[mi][1] = __builtin_amdgcn_mfma_f32_16x16x32_bf16(a, b1, acc[mi][1], 0, 0, 0);
    }
  }

  __syncthreads();   // reuse sA as h1 tile [64 rows][256B], swizzled (ds_write path)
#pragma unroll
  for (int ni = 0; ni < 2; ++ni) {
    int colj = j0 + ni * 16 + lrow;
    float bv = bias[colj];
#pragma unroll
    for (int mi = 0; mi < 4; ++mi) {
#pragma unroll
      for (int r = 0; r < 4; ++r) {
        int row = mi * 16 + lk * 4 + r;
        float v = fmaxf(acc[mi][ni][r] + bv, 0.f);
        int byte = (row * 256 + colj * 2) ^ ((row & 7) << 4);
        *(bf16*)(sA + byte) = __float2bfloat16(v);
      }
    }
  }
  __syncthreads();

  const int jo = w * 16;
  f32x4 acc2[4];
#pragma unroll
  for (int mi = 0; mi < 4; ++mi) acc2[mi] = (f32x4){0.f, 0.f, 0.f, 0.f};

#pragma unroll
  for (int kt = 0; kt < 4; ++kt) {
    bfrag b = *(const bfrag*)(WoT + (size_t)(jo + lrow) * DIM + kt * 32 + lk * 8);
#pragma unroll
    for (int mi = 0; mi < 4; ++mi) {
      int row = mi * 16 + lrow;
      int byte = (row * 256 + kt * 64 + lk * 16) ^ ((row & 7) << 4);
      bfrag a = *(const bfrag*)(sA + byte);
      acc2[mi] = __builtin_amdgcn_mfma_f32_16x16x32_bf16(a, b, acc2[mi], 0, 0, 0);
    }
  }

  int colj = jo + lrow;
  float bv = bo[colj];
#pragma unroll
  for (int mi = 0; mi < 4; ++mi) {
#pragma unroll
    for (int r = 0; r < 4; ++r) {
      int n = base + mi * 16 + lk * 4 + r;
      if (n < N_NODES)
        out[(size_t)n * ODIM + colj] = 1.f / (1.f + __expf(-(acc2[mi][r] + bv)));
    }
  }
}

extern "C" void kernel_launch(void* const* d_in, const int* in_sizes, int n_in,
                              void* d_out, int out_size, void* d_ws, size_t ws_size,
                              hipStream_t stream) {
  const float* x     = (const float*)d_in[0];
  const int*   ei    = (const int*)d_in[1];
  const float* w_l0  = (const float*)d_in[2];
  const float* b_l0  = (const float*)d_in[3];
  const float* w_r0  = (const float*)d_in[4];
  const float* w_l1  = (const float*)d_in[5];
  const float* b_l1  = (const float*)d_in[6];
  const float* w_r1  = (const float*)d_in[7];
  const float* w_out = (const float*)d_in[8];
  const float* b_out = (const float*)d_in[9];
  float* out = (float*)d_out;

  const int* src = ei;
  const int* dst = ei + N_EDGES;

  char* ws = (char*)d_ws;
  int*      rowptr = (int*)(ws);                          // 400,004 B
  int*      gcur   = (int*)(ws + (512u << 10));           // 3,136 B
  int*      col    = (int*)(ws + (1u << 20));             // 6.4 MB (byte offsets)
  uint32_t* bdata  = (uint32_t*)(ws + (8u << 20));        // 8.03 MB (dead after k_csr)
  uint8_t*  x8     = (uint8_t*)(ws + (8u << 20));         // 12.8 MB (overlays bdata)
  uint8_t*  h08    = (uint8_t*)(ws + (8u << 20));         // 12.8 MB (overlays x8 after layer-0 agg)
  bf16*     WT0    = (bf16*)(ws + (21u << 20));           // 64 KB
  bf16*     WT1    = (bf16*)(ws + (21u << 20) + 65536);   // 64 KB
  bf16*     WoT    = (bf16*)(ws + (21u << 20) + 131072);  // 16 KB
  bf16*     aggb   = (bf16*)(ws + (22ull << 20));         // 25.6 MB
  bf16*     h0b    = (bf16*)(ws + (48ull << 20));         // 25.6 MB
  bf16*     xb     = (bf16*)(ws + (74ull << 20));         // 25.6 MB (~99.6 MB total)

  // --- CSR build first (bdata region is then reused for fp8 tables) ---
  hipMemsetAsync(gcur, 0, NREP * CB * sizeof(int), stream);
  k_bucket<<<(N_EDGES + EPB - 1) / EPB, 1024, 0, stream>>>(src, dst, gcur, bdata);
  k_csr   <<<CB, 256, 0, stream>>>(bdata, gcur, rowptr, col);

  // --- precompute (x -> bf16 + fp8; weights) ---
  k_cvt  <<<(N_NODES * DIM / 4 + 255) / 256, 256, 0, stream>>>(x, xb, x8);
  k_prepw<<<(65536 + 8192 + 255) / 256, 256, 0, stream>>>(w_l0, w_r0, w_l1, w_r1, w_out,
                                                          WT0, WT1, WoT);

  const int ablocks = (N_NODES * 64 + 255) / 256;
  const int gblocks = (N_NODES + NPB - 1) / NPB;

  // --- layer 0 ---
  k_agg <<<ablocks, 256, 0, stream>>>(x8, rowptr, col, aggb);
  k_sage<<<gblocks, 256, 0, stream>>>(aggb, xb, WT0, b_l0, h0b, h08);

  // --- layer 1 + head ---
  k_agg<<<ablocks, 256, 0, stream>>>(h08, rowptr, col, aggb);
  k_out<<<gblocks, 256, 0, stream>>>(aggb, h0b, WT1, b_l1, WoT, b_out, out);
}